// Round 8
// baseline (421.446 us; speedup 1.0000x reference)
//
#include <hip/hip_runtime.h>
#include <math.h>

#define B 2
#define S 48
#define D 256
#define H 8
#define DH 32
#define N (S*S)      // 2304
#define BN (B*N)     // 4608
#define BH (B*H)     // 16
#define KS 6         // split-K over keys
#define KPZ (N/KS)   // 384 = 6 tiles of 64
#define NE ((size_t)BN*D)
#define BHN (BH*N)
#define GRID 432     // <= guaranteed-resident capacity (>=2 blocks/CU x 256 CU)

typedef _Float16 half8 __attribute__((ext_vector_type(8)));
typedef _Float16 half4_t __attribute__((ext_vector_type(4)));
typedef unsigned short ushort8_t __attribute__((ext_vector_type(8)));
typedef float floatx4 __attribute__((ext_vector_type(4)));

__device__ __forceinline__ void split8(const float* v, half8* hi, half8* lo) {
    #pragma unroll
    for (int j = 0; j < 8; j++) {
        _Float16 h = (_Float16)v[j];
        (*hi)[j] = h;
        (*lo)[j] = (_Float16)(v[j] - (float)h);
    }
}

// Software grid barrier. Safe because GRID (432) < guaranteed resident
// capacity (>=2 blocks/CU * 256 CU = 512 at <=256 VGPR, 20.5KB LDS).
// Agent-scope fences handle cross-XCD L2 visibility. Bounded spin failsafe.
__device__ __forceinline__ void grid_barrier(unsigned* cnt) {
    __threadfence();
    __syncthreads();
    if (threadIdx.x == 0) {
        __hip_atomic_fetch_add(cnt, 1u, __ATOMIC_ACQ_REL, __HIP_MEMORY_SCOPE_AGENT);
        long guard = 0;
        while (__hip_atomic_load(cnt, __ATOMIC_ACQUIRE, __HIP_MEMORY_SCOPE_AGENT) < GRID
               && ++guard < (1L << 31)) { }
    }
    __syncthreads();
    __threadfence();
}

__global__ __launch_bounds__(256, 2) void fused_kernel(
    const float* __restrict__ x,
    const float* __restrict__ Wq, const float* __restrict__ bq,
    const float* __restrict__ Wk, const float* __restrict__ bk,
    const float* __restrict__ Wv, const float* __restrict__ bv,
    const float* __restrict__ Wo, const float* __restrict__ bo,
    float* __restrict__ out,
    unsigned* __restrict__ counters,
    _Float16* __restrict__ ctx_part, float* __restrict__ lpart,
    _Float16* __restrict__ qbuf, _Float16* __restrict__ kbuf,
    _Float16* __restrict__ vtbuf)
{
    __shared__ __align__(16) unsigned char smem[20480];

    const int t = threadIdx.x;
    const int bid = blockIdx.x;
    const int wv2 = t >> 6, lane = t & 63, l15 = lane & 15, quad = lane >> 4;

    // ================= Phase 1: QKV projection (864 units, 2/block) =======
    {
        _Float16* BhS = (_Float16*)smem;       // 64*72
        _Float16* BlS = BhS + 64 * 72;
        for (int u = bid; u < 864; u += GRID) {
            const int z = u / 288, rem = u % 288;
            const int rowb = (rem >> 2) * 64, colb = (rem & 3) * 64;
            const float* W    = (z == 0) ? Wq : (z == 1) ? Wk : Wv;
            const float* bias = (z == 0) ? bq : (z == 1) ? bk : bv;
            const float scale = (z == 0) ? rsqrtf((float)DH) * 1.44269504f : 1.0f;
            const int grow = rowb + wv2 * 16 + l15;
            floatx4 acc[4] = {{0,0,0,0},{0,0,0,0},{0,0,0,0},{0,0,0,0}};

            for (int kb0 = 0; kb0 < D; kb0 += 64) {
                __syncthreads();
                #pragma unroll
                for (int i = 0; i < 2; i++) {
                    int uu = i * 256 + t;
                    int cc = uu & 63, k0 = (uu >> 6) * 8;
                    float v[8];
                    #pragma unroll
                    for (int j = 0; j < 8; j++)
                        v[j] = W[(size_t)(kb0 + k0 + j) * D + colb + cc];
                    half8 hi, lo;
                    split8(v, &hi, &lo);
                    *(half8*)(BhS + cc * 72 + k0) = hi;
                    *(half8*)(BlS + cc * 72 + k0) = lo;
                }
                __syncthreads();
                #pragma unroll
                for (int ksx = 0; ksx < 2; ksx++) {
                    const float* xp = x + (size_t)grow * D + kb0 + ksx * 32 + quad * 8;
                    float4 x0 = *(const float4*)xp;
                    float4 x1 = *(const float4*)(xp + 4);
                    float v[8] = {x0.x, x0.y, x0.z, x0.w, x1.x, x1.y, x1.z, x1.w};
                    half8 ah, al;
                    split8(v, &ah, &al);
                    #pragma unroll
                    for (int cg = 0; cg < 4; cg++) {
                        half8 bh8 = *(const half8*)(BhS + (cg * 16 + l15) * 72 + ksx * 32 + quad * 8);
                        half8 bl8 = *(const half8*)(BlS + (cg * 16 + l15) * 72 + ksx * 32 + quad * 8);
                        acc[cg] = __builtin_amdgcn_mfma_f32_16x16x32_f16(ah, bh8, acc[cg], 0, 0, 0);
                        acc[cg] = __builtin_amdgcn_mfma_f32_16x16x32_f16(al, bh8, acc[cg], 0, 0, 0);
                        acc[cg] = __builtin_amdgcn_mfma_f32_16x16x32_f16(ah, bl8, acc[cg], 0, 0, 0);
                    }
                }
            }

            const int bb = (rowb >= N) ? 1 : 0;
            #pragma unroll
            for (int cg = 0; cg < 4; cg++) {
                int col = colb + cg * 16 + l15;
                int hh = col >> 5, dh = col & 31;
                float bs = bias[col];
                if (z < 2) {
                    _Float16* op = (z == 0) ? qbuf : kbuf;
                    #pragma unroll
                    for (int r = 0; r < 4; r++) {
                        int n = rowb + wv2 * 16 + quad * 4 + r - bb * N;
                        float v = (acc[cg][r] + bs) * scale;
                        op[((size_t)(bb * H + hh) * N + n) * DH + dh] = (_Float16)v;
                    }
                } else {
                    int n0 = rowb + wv2 * 16 + quad * 4 - bb * N;
                    half4_t pk;
                    #pragma unroll
                    for (int r = 0; r < 4; r++) pk[r] = (_Float16)(acc[cg][r] + bs);
                    *(half4_t*)(vtbuf + ((size_t)(bb * H + hh) * DH + dh) * N + n0) = pk;
                }
            }
        }
    }
    grid_barrier(&counters[0]);

    // ================= Phase 2: attention (1728 units, 4/block) ===========
    {
        _Float16* Ks = (_Float16*)smem;        // 64*40
        _Float16* Vt = Ks + 64 * 40;           // 32*72 [d][key]
        const int skey = t >> 2, sd0 = (t & 3) * 8;
        const int svd = t >> 3, svk = (t & 7) * 8;

        for (int u = bid; u < 1728; u += GRID) {
            const int xq = u / 96, rem = u % 96;
            const int bh = rem / 6, kz = rem % 6;
            const int qbase = xq * 128 + wv2 * 32;

            half8 bq8[2];
            #pragma unroll
            for (int qg = 0; qg < 2; qg++)
                bq8[qg] = *(const half8*)(qbuf +
                    ((size_t)bh * N + qbase + qg * 16 + l15) * DH + quad * 8);

            floatx4 acc[2][2] = {{{0,0,0,0},{0,0,0,0}},{{0,0,0,0},{0,0,0,0}}};
            float lsum[2] = {0.f, 0.f};

            for (int it = 0; it < KPZ / 64; it++) {
                const int key0 = kz * KPZ + it * 64;
                __syncthreads();
                *(ushort8_t*)(Ks + skey * 40 + sd0) =
                    *(const ushort8_t*)(kbuf + ((size_t)bh * N + key0 + skey) * DH + sd0);
                *(ushort8_t*)(Vt + svd * 72 + svk) =
                    *(const ushort8_t*)(vtbuf + ((size_t)bh * DH + svd) * N + key0 + svk);
                __syncthreads();

                #pragma unroll
                for (int kg = 0; kg < 4; kg++) {
                    half8 ka = *(const half8*)(Ks + (kg * 16 + l15) * 40 + quad * 8);
                    half4_t va0 = *(const half4_t*)(Vt + l15 * 72 + kg * 16 + quad * 4);
                    half4_t va1 = *(const half4_t*)(Vt + (16 + l15) * 72 + kg * 16 + quad * 4);
                    #pragma unroll
                    for (int qg = 0; qg < 2; qg++) {
                        floatx4 s = {0, 0, 0, 0};
                        s = __builtin_amdgcn_mfma_f32_16x16x32_f16(ka, bq8[qg], s, 0, 0, 0);
                        half4_t pf;
                        #pragma unroll
                        for (int r = 0; r < 4; r++) {
                            float p = exp2f(s[r]);
                            lsum[qg] += p;
                            pf[r] = (_Float16)p;
                        }
                        acc[qg][0] = __builtin_amdgcn_mfma_f32_16x16x16f16(va0, pf, acc[qg][0], 0, 0, 0);
                        acc[qg][1] = __builtin_amdgcn_mfma_f32_16x16x16f16(va1, pf, acc[qg][1], 0, 0, 0);
                    }
                }
            }

            const int bb = bh >> 3, hh = bh & 7;
            #pragma unroll
            for (int qg = 0; qg < 2; qg++) {
                float ls = lsum[qg];
                ls += __shfl_xor(ls, 16);
                ls += __shfl_xor(ls, 32);
                int q = qbase + qg * 16 + l15;
                if (quad == 0) lpart[(size_t)kz * BHN + bh * N + q] = ls;
                _Float16* crow = ctx_part + (size_t)kz * NE + ((size_t)bb * N + q) * D + hh * DH;
                half4_t c0, c1;
                #pragma unroll
                for (int r = 0; r < 4; r++) {
                    c0[r] = (_Float16)acc[qg][0][r];
                    c1[r] = (_Float16)acc[qg][1][r];
                }
                *(half4_t*)(crow + quad * 4)      = c0;
                *(half4_t*)(crow + 16 + quad * 4) = c1;
            }
        }
    }
    grid_barrier(&counters[1]);

    // ================= Phase 3: merge + output projection (288 units) =====
    if (bid < 288) {
        _Float16* BhS = (_Float16*)smem;
        _Float16* BlS = BhS + 64 * 72;
        float* Linv = (float*)(smem + 18432);  // 64*8 floats
        const int rowb = (bid >> 2) * 64, colb = (bid & 3) * 64;
        const int grow = rowb + wv2 * 16 + l15;

        #pragma unroll
        for (int i = 0; i < 2; i++) {
            int idx = i * 256 + t;
            int r = idx >> 3, hh = idx & 7;
            int row = rowb + r;
            int bb = (row >= N) ? 1 : 0;
            int bhn = (bb * H + hh) * N + (row - bb * N);
            float ls = 0.f;
            #pragma unroll
            for (int zz = 0; zz < KS; zz++) ls += lpart[(size_t)zz * BHN + bhn];
            Linv[idx] = 1.0f / ls;
        }

        floatx4 acc[4] = {{0,0,0,0},{0,0,0,0},{0,0,0,0},{0,0,0,0}};

        for (int kb0 = 0; kb0 < D; kb0 += 64) {
            __syncthreads();
            #pragma unroll
            for (int i = 0; i < 2; i++) {
                int uu = i * 256 + t;
                int cc = uu & 63, k0 = (uu >> 6) * 8;
                float v[8];
                #pragma unroll
                for (int j = 0; j < 8; j++)
                    v[j] = Wo[(size_t)(kb0 + k0 + j) * D + colb + cc];
                half8 hi, lo;
                split8(v, &hi, &lo);
                *(half8*)(BhS + cc * 72 + k0) = hi;
                *(half8*)(BlS + cc * 72 + k0) = lo;
            }
            __syncthreads();
            #pragma unroll
            for (int ksx = 0; ksx < 2; ksx++) {
                const int kcol = kb0 + ksx * 32 + quad * 8;
                float linv = Linv[(wv2 * 16 + l15) * 8 + (kcol >> 5)];
                float v[8] = {};
                #pragma unroll
                for (int zz = 0; zz < KS; zz++) {
                    half8 h = *(const half8*)(ctx_part + (size_t)zz * NE + (size_t)grow * D + kcol);
                    #pragma unroll
                    for (int j = 0; j < 8; j++) v[j] += (float)h[j];
                }
                #pragma unroll
                for (int j = 0; j < 8; j++) v[j] *= linv;
                half8 ah, al;
                split8(v, &ah, &al);
                #pragma unroll
                for (int cg = 0; cg < 4; cg++) {
                    half8 bh8 = *(const half8*)(BhS + (cg * 16 + l15) * 72 + ksx * 32 + quad * 8);
                    half8 bl8 = *(const half8*)(BlS + (cg * 16 + l15) * 72 + ksx * 32 + quad * 8);
                    acc[cg] = __builtin_amdgcn_mfma_f32_16x16x32_f16(ah, bh8, acc[cg], 0, 0, 0);
                    acc[cg] = __builtin_amdgcn_mfma_f32_16x16x32_f16(al, bh8, acc[cg], 0, 0, 0);
                    acc[cg] = __builtin_amdgcn_mfma_f32_16x16x32_f16(ah, bl8, acc[cg], 0, 0, 0);
                }
            }
        }

        #pragma unroll
        for (int cg = 0; cg < 4; cg++) {
            int col = colb + cg * 16 + l15;
            float bs = bo[col];
            #pragma unroll
            for (int r = 0; r < 4; r++) {
                int row = rowb + wv2 * 16 + quad * 4 + r;
                out[(size_t)row * D + col] = acc[cg][r] + bs;
            }
        }
    }
}

extern "C" void kernel_launch(void* const* d_in, const int* in_sizes, int n_in,
                              void* d_out, int out_size, void* d_ws, size_t ws_size,
                              hipStream_t stream)
{
    const float* x  = (const float*)d_in[0];
    const float* Wq = (const float*)d_in[1];
    const float* bq = (const float*)d_in[2];
    const float* Wk = (const float*)d_in[3];
    const float* bk = (const float*)d_in[4];
    const float* Wv = (const float*)d_in[5];
    const float* bv = (const float*)d_in[6];
    const float* Wo = (const float*)d_in[7];
    const float* bo = (const float*)d_in[8];
    float* out = (float*)d_out;

    unsigned* counters = (unsigned*)d_ws;                       // 64 B
    _Float16* ctx_part = (_Float16*)((char*)d_ws + 64);         // KS*NE halfs
    float* lpart    = (float*)(ctx_part + (size_t)KS * NE);     // KS*BHN fp32
    _Float16* qbuf  = (_Float16*)(lpart + (size_t)KS * BHN);
    _Float16* kbuf  = qbuf + NE;
    _Float16* vtbuf = kbuf + NE;

    hipMemsetAsync(d_ws, 0, 64, stream);   // zero barrier counters

    fused_kernel<<<dim3(GRID), dim3(256), 0, stream>>>(
        x, Wq, bq, Wk, bk, Wv, bv, Wo, bo, out,
        counters, ctx_part, lpart, qbuf, kbuf, vtbuf);
}

// Round 9
// 134.273 us; speedup vs baseline: 3.1387x; 3.1387x over previous
//
#include <hip/hip_runtime.h>
#include <math.h>

#define B 2
#define S 48
#define D 256
#define H 8
#define DH 32
#define N (S*S)      // 2304
#define BN (B*N)     // 4608
#define BH (B*H)     // 16
#define KS 6         // split-K over keys
#define KPZ (N/KS)   // 384 = 6 tiles of 64
#define NE ((size_t)BN*D)
#define BHN (BH*N)

typedef _Float16 half8 __attribute__((ext_vector_type(8)));
typedef _Float16 half4_t __attribute__((ext_vector_type(4)));
typedef unsigned short ushort8_t __attribute__((ext_vector_type(8)));
typedef float floatx4 __attribute__((ext_vector_type(4)));

__device__ __forceinline__ half8 cvt8(const float* v) {
    half8 h;
    #pragma unroll
    for (int j = 0; j < 8; j++) h[j] = (_Float16)v[j];
    return h;
}

// ---------------------------------------------------------------------------
// QKV projection, plain-fp16 MFMA (1 mfma/step). A-fragments loaded directly
// from global x (contiguous 8 floats/lane = the A-frag) and converted
// in-register — no A LDS. W transposed+converted inline to LDS.
// grid (72, 4, 3). Outputs: q,k (BH,N,DH) fp16 (q pre-scaled log2e/sqrt(DH));
// v TRANSPOSED (BH,DH,N) fp16.
// ---------------------------------------------------------------------------
__global__ __launch_bounds__(256) void proj_kernel(
    const float* __restrict__ x,
    const float* __restrict__ Wq, const float* __restrict__ bq,
    const float* __restrict__ Wk, const float* __restrict__ bk,
    const float* __restrict__ Wv, const float* __restrict__ bv,
    _Float16* __restrict__ qbuf, _Float16* __restrict__ kbuf,
    _Float16* __restrict__ vtbuf)
{
    __shared__ __align__(16) _Float16 BhS[64 * 72];

    const int z = blockIdx.z;
    const float* W    = (z == 0) ? Wq : (z == 1) ? Wk : Wv;
    const float* bias = (z == 0) ? bq : (z == 1) ? bk : bv;
    const float scale = (z == 0) ? rsqrtf((float)DH) * 1.44269504f : 1.0f;

    const int t = threadIdx.x;
    const int wv2 = t >> 6, lane = t & 63, l15 = lane & 15, quad = lane >> 4;
    const int rowb = blockIdx.x * 64;
    const int colb = blockIdx.y * 64;
    const int grow = rowb + wv2 * 16 + l15;        // this lane's A row
    floatx4 acc[4] = {{0,0,0,0},{0,0,0,0},{0,0,0,0},{0,0,0,0}};

    for (int kb0 = 0; kb0 < D; kb0 += 64) {
        __syncthreads();
        // B: W transposed gather (coalesced across cc) -> fp16 in LDS
        #pragma unroll
        for (int i = 0; i < 2; i++) {
            int u = i * 256 + t;
            int cc = u & 63, k0 = (u >> 6) * 8;
            float v[8];
            #pragma unroll
            for (int j = 0; j < 8; j++)
                v[j] = W[(size_t)(kb0 + k0 + j) * D + colb + cc];
            *(half8*)(BhS + cc * 72 + k0) = cvt8(v);
        }
        __syncthreads();
        #pragma unroll
        for (int ksx = 0; ksx < 2; ksx++) {
            const float* xp = x + (size_t)grow * D + kb0 + ksx * 32 + quad * 8;
            float4 x0 = *(const float4*)xp;
            float4 x1 = *(const float4*)(xp + 4);
            float v[8] = {x0.x, x0.y, x0.z, x0.w, x1.x, x1.y, x1.z, x1.w};
            half8 ah = cvt8(v);
            #pragma unroll
            for (int cg = 0; cg < 4; cg++) {
                half8 bh8 = *(const half8*)(BhS + (cg * 16 + l15) * 72 + ksx * 32 + quad * 8);
                acc[cg] = __builtin_amdgcn_mfma_f32_16x16x32_f16(ah, bh8, acc[cg], 0, 0, 0);
            }
        }
    }

    const int bb = (rowb >= N) ? 1 : 0;
    #pragma unroll
    for (int cg = 0; cg < 4; cg++) {
        int col = colb + cg * 16 + l15;
        int hh = col >> 5, dh = col & 31;
        float bs = bias[col];
        if (z < 2) {
            _Float16* op = (z == 0) ? qbuf : kbuf;
            #pragma unroll
            for (int r = 0; r < 4; r++) {
                int n = rowb + wv2 * 16 + quad * 4 + r - bb * N;
                float v = (acc[cg][r] + bs) * scale;
                op[((size_t)(bb * H + hh) * N + n) * DH + dh] = (_Float16)v;
            }
        } else {
            int n0 = rowb + wv2 * 16 + quad * 4 - bb * N;
            half4_t pk;
            #pragma unroll
            for (int r = 0; r < 4; r++) pk[r] = (_Float16)(acc[cg][r] + bs);
            *(half4_t*)(vtbuf + ((size_t)(bb * H + hh) * DH + dh) * N + n0) = pk;
        }
    }
}

// ---------------------------------------------------------------------------
// Flash attention (S^T register-P). grid (18, BH, KS), 256 thr = 4 waves x
// 32 queries. QK^T: one 16x16x32 mfma per 16-key group; exp2 in place;
// P^T C-frag feeds PV (A=V^T from LDS, K=16 mfma). V pre-transposed ->
// staging is a straight b128 copy. Fixed-max softmax, linear split-K
// partials written in FP16.
// ---------------------------------------------------------------------------
__global__ __launch_bounds__(256) void attn_kernel(
    const _Float16* __restrict__ qbuf, const _Float16* __restrict__ kbuf,
    const _Float16* __restrict__ vtbuf,
    _Float16* __restrict__ ctx_part, float* __restrict__ lpart)
{
    __shared__ __align__(16) _Float16 Ks[64 * 40];
    __shared__ __align__(16) _Float16 Vt[32 * 72];   // [d][key]

    const int t = threadIdx.x;
    const int wv2 = t >> 6, lane = t & 63, l15 = lane & 15, quad = lane >> 4;
    const int bh = blockIdx.y, kz = blockIdx.z;
    const int qbase = blockIdx.x * 128 + wv2 * 32;

    half8 bq8[2];
    #pragma unroll
    for (int qg = 0; qg < 2; qg++)
        bq8[qg] = *(const half8*)(qbuf +
            ((size_t)bh * N + qbase + qg * 16 + l15) * DH + quad * 8);

    floatx4 acc[2][2] = {{{0,0,0,0},{0,0,0,0}},{{0,0,0,0},{0,0,0,0}}};
    float lsum[2] = {0.f, 0.f};

    const int skey = t >> 2, sd0 = (t & 3) * 8;      // K staging
    const int svd = t >> 3, svk = (t & 7) * 8;       // V staging

    for (int it = 0; it < KPZ / 64; it++) {
        const int key0 = kz * KPZ + it * 64;
        __syncthreads();
        *(ushort8_t*)(Ks + skey * 40 + sd0) =
            *(const ushort8_t*)(kbuf + ((size_t)bh * N + key0 + skey) * DH + sd0);
        *(ushort8_t*)(Vt + svd * 72 + svk) =
            *(const ushort8_t*)(vtbuf + ((size_t)bh * DH + svd) * N + key0 + svk);
        __syncthreads();

        #pragma unroll
        for (int kg = 0; kg < 4; kg++) {
            half8 ka = *(const half8*)(Ks + (kg * 16 + l15) * 40 + quad * 8);
            half4_t va0 = *(const half4_t*)(Vt + l15 * 72 + kg * 16 + quad * 4);
            half4_t va1 = *(const half4_t*)(Vt + (16 + l15) * 72 + kg * 16 + quad * 4);
            #pragma unroll
            for (int qg = 0; qg < 2; qg++) {
                floatx4 s = {0, 0, 0, 0};
                s = __builtin_amdgcn_mfma_f32_16x16x32_f16(ka, bq8[qg], s, 0, 0, 0);
                half4_t pf;
                #pragma unroll
                for (int r = 0; r < 4; r++) {
                    float p = exp2f(s[r]);
                    lsum[qg] += p;
                    pf[r] = (_Float16)p;
                }
                acc[qg][0] = __builtin_amdgcn_mfma_f32_16x16x16f16(va0, pf, acc[qg][0], 0, 0, 0);
                acc[qg][1] = __builtin_amdgcn_mfma_f32_16x16x16f16(va1, pf, acc[qg][1], 0, 0, 0);
            }
        }
    }

    const int bb = bh >> 3, hh = bh & 7;
    #pragma unroll
    for (int qg = 0; qg < 2; qg++) {
        float ls = lsum[qg];
        ls += __shfl_xor(ls, 16);
        ls += __shfl_xor(ls, 32);
        int q = qbase + qg * 16 + l15;
        if (quad == 0) lpart[(size_t)kz * BHN + bh * N + q] = ls;
        _Float16* crow = ctx_part + (size_t)kz * NE + ((size_t)bb * N + q) * D + hh * DH;
        half4_t c0, c1;
        #pragma unroll
        for (int r = 0; r < 4; r++) {
            c0[r] = (_Float16)acc[qg][0][r];
            c1[r] = (_Float16)acc[qg][1][r];
        }
        *(half4_t*)(crow + quad * 4)      = c0;
        *(half4_t*)(crow + 16 + quad * 4) = c1;
    }
}

// ---------------------------------------------------------------------------
// Output projection with fused merge, plain-fp16 MFMA. A-frags built
// in-register from the KS fp16 partials (coalesced 16B loads) normalized via
// a per-block Linv LDS table; Wo transposed+converted inline. grid (72, 4).
// ---------------------------------------------------------------------------
__global__ __launch_bounds__(256) void outproj_kernel(
    const _Float16* __restrict__ ctx_part, const float* __restrict__ lpart,
    const float* __restrict__ Wo, const float* __restrict__ bo,
    float* __restrict__ out)
{
    __shared__ __align__(16) _Float16 BhS[64 * 72];
    __shared__ float Linv[64 * 8];

    const int t = threadIdx.x;
    const int wv2 = t >> 6, lane = t & 63, l15 = lane & 15, quad = lane >> 4;
    const int rowb = blockIdx.x * 64;
    const int colb = blockIdx.y * 64;
    const int grow = rowb + wv2 * 16 + l15;

    // per-block merged 1/l table: rows 0..63 x heads 0..7
    #pragma unroll
    for (int i = 0; i < 2; i++) {
        int idx = i * 256 + t;
        int r = idx >> 3, hh = idx & 7;
        int row = rowb + r;
        int bb = (row >= N) ? 1 : 0;
        int bhn = (bb * H + hh) * N + (row - bb * N);
        float ls = 0.f;
        #pragma unroll
        for (int zz = 0; zz < KS; zz++) ls += lpart[(size_t)zz * BHN + bhn];
        Linv[idx] = 1.0f / ls;
    }

    floatx4 acc[4] = {{0,0,0,0},{0,0,0,0},{0,0,0,0},{0,0,0,0}};

    for (int kb0 = 0; kb0 < D; kb0 += 64) {
        __syncthreads();
        #pragma unroll
        for (int i = 0; i < 2; i++) {
            int u = i * 256 + t;
            int cc = u & 63, k0 = (u >> 6) * 8;
            float v[8];
            #pragma unroll
            for (int j = 0; j < 8; j++)
                v[j] = Wo[(size_t)(kb0 + k0 + j) * D + colb + cc];
            *(half8*)(BhS + cc * 72 + k0) = cvt8(v);
        }
        __syncthreads();
        #pragma unroll
        for (int ksx = 0; ksx < 2; ksx++) {
            const int kcol = kb0 + ksx * 32 + quad * 8;   // head const per frag
            float linv = Linv[(wv2 * 16 + l15) * 8 + (kcol >> 5)];
            float v[8] = {};
            #pragma unroll
            for (int zz = 0; zz < KS; zz++) {
                half8 h = *(const half8*)(ctx_part + (size_t)zz * NE + (size_t)grow * D + kcol);
                #pragma unroll
                for (int j = 0; j < 8; j++) v[j] += (float)h[j];
            }
            #pragma unroll
            for (int j = 0; j < 8; j++) v[j] *= linv;
            half8 ah = cvt8(v);
            #pragma unroll
            for (int cg = 0; cg < 4; cg++) {
                half8 bh8 = *(const half8*)(BhS + (cg * 16 + l15) * 72 + ksx * 32 + quad * 8);
                acc[cg] = __builtin_amdgcn_mfma_f32_16x16x32_f16(ah, bh8, acc[cg], 0, 0, 0);
            }
        }
    }

    #pragma unroll
    for (int cg = 0; cg < 4; cg++) {
        int col = colb + cg * 16 + l15;
        float bs = bo[col];
        #pragma unroll
        for (int r = 0; r < 4; r++) {
            int row = rowb + wv2 * 16 + quad * 4 + r;
            out[(size_t)row * D + col] = acc[cg][r] + bs;
        }
    }
}

extern "C" void kernel_launch(void* const* d_in, const int* in_sizes, int n_in,
                              void* d_out, int out_size, void* d_ws, size_t ws_size,
                              hipStream_t stream)
{
    const float* x  = (const float*)d_in[0];
    const float* Wq = (const float*)d_in[1];
    const float* bq = (const float*)d_in[2];
    const float* Wk = (const float*)d_in[3];
    const float* bk = (const float*)d_in[4];
    const float* Wv = (const float*)d_in[5];
    const float* bv = (const float*)d_in[6];
    const float* Wo = (const float*)d_in[7];
    const float* bo = (const float*)d_in[8];
    float* out = (float*)d_out;

    _Float16* ctx_part = (_Float16*)d_ws;                   // KS*NE halfs
    float* lpart    = (float*)(ctx_part + (size_t)KS * NE); // KS*BHN fp32
    _Float16* qbuf  = (_Float16*)(lpart + (size_t)KS * BHN);
    _Float16* kbuf  = qbuf + NE;
    _Float16* vtbuf = kbuf + NE;

    proj_kernel<<<dim3(BN / 64, D / 64, 3), 256, 0, stream>>>(
        x, Wq, bq, Wk, bk, Wv, bv, qbuf, kbuf, vtbuf);

    attn_kernel<<<dim3(N / 128, BH, KS), 256, 0, stream>>>(
        qbuf, kbuf, vtbuf, ctx_part, lpart);

    outproj_kernel<<<dim3(BN / 64, D / 64), 256, 0, stream>>>(
        ctx_part, lpart, Wo, bo, out);
}

// Round 10
// 132.185 us; speedup vs baseline: 3.1883x; 1.0158x over previous
//
#include <hip/hip_runtime.h>
#include <math.h>

#define B 2
#define S 48
#define D 256
#define H 8
#define DH 32
#define N (S*S)      // 2304
#define BN (B*N)     // 4608
#define BH (B*H)     // 16
#define KS 6         // split-K over keys
#define KPZ (N/KS)   // 384 = 3 tiles of 128
#define NE ((size_t)BN*D)
#define BHN (BH*N)

typedef _Float16 half8 __attribute__((ext_vector_type(8)));
typedef _Float16 half4_t __attribute__((ext_vector_type(4)));
typedef unsigned short ushort8_t __attribute__((ext_vector_type(8)));
typedef float floatx4 __attribute__((ext_vector_type(4)));

__device__ __forceinline__ half8 cvt8(const float* v) {
    half8 h;
    #pragma unroll
    for (int j = 0; j < 8; j++) h[j] = (_Float16)v[j];
    return h;
}

// ---------------------------------------------------------------------------
// QKV projection, plain-fp16 MFMA, 64x128 tiles (x re-read 2x instead of 4x).
// A-frags direct from global x; W transposed+converted inline to LDS.
// grid (72, 2, 3). Outputs: q,k (BH,N,DH) fp16 (q pre-scaled log2e/sqrt(DH));
// v TRANSPOSED (BH,DH,N) fp16.
// ---------------------------------------------------------------------------
__global__ __launch_bounds__(256) void proj_kernel(
    const float* __restrict__ x,
    const float* __restrict__ Wq, const float* __restrict__ bq,
    const float* __restrict__ Wk, const float* __restrict__ bk,
    const float* __restrict__ Wv, const float* __restrict__ bv,
    _Float16* __restrict__ qbuf, _Float16* __restrict__ kbuf,
    _Float16* __restrict__ vtbuf)
{
    __shared__ __align__(16) _Float16 BhS[128 * 72];   // 18.4 KB

    const int z = blockIdx.z;
    const float* W    = (z == 0) ? Wq : (z == 1) ? Wk : Wv;
    const float* bias = (z == 0) ? bq : (z == 1) ? bk : bv;
    const float scale = (z == 0) ? rsqrtf((float)DH) * 1.44269504f : 1.0f;

    const int t = threadIdx.x;
    const int wv2 = t >> 6, lane = t & 63, l15 = lane & 15, quad = lane >> 4;
    const int rowb = blockIdx.x * 64;
    const int colb = blockIdx.y * 128;
    const int grow = rowb + wv2 * 16 + l15;
    floatx4 acc[8] = {{0,0,0,0},{0,0,0,0},{0,0,0,0},{0,0,0,0},
                      {0,0,0,0},{0,0,0,0},{0,0,0,0},{0,0,0,0}};

    for (int kb0 = 0; kb0 < D; kb0 += 64) {
        __syncthreads();
        // B: 128 cols x 64 k, coalesced across cc
        #pragma unroll
        for (int i = 0; i < 4; i++) {
            int u = i * 256 + t;
            int cc = u & 127, k0 = (u >> 7) * 8;
            float v[8];
            #pragma unroll
            for (int j = 0; j < 8; j++)
                v[j] = W[(size_t)(kb0 + k0 + j) * D + colb + cc];
            *(half8*)(BhS + cc * 72 + k0) = cvt8(v);
        }
        __syncthreads();
        #pragma unroll
        for (int ksx = 0; ksx < 2; ksx++) {
            const float* xp = x + (size_t)grow * D + kb0 + ksx * 32 + quad * 8;
            float4 x0 = *(const float4*)xp;
            float4 x1 = *(const float4*)(xp + 4);
            float v[8] = {x0.x, x0.y, x0.z, x0.w, x1.x, x1.y, x1.z, x1.w};
            half8 ah = cvt8(v);
            #pragma unroll
            for (int cg = 0; cg < 8; cg++) {
                half8 bh8 = *(const half8*)(BhS + (cg * 16 + l15) * 72 + ksx * 32 + quad * 8);
                acc[cg] = __builtin_amdgcn_mfma_f32_16x16x32_f16(ah, bh8, acc[cg], 0, 0, 0);
            }
        }
    }

    const int bb = (rowb >= N) ? 1 : 0;
    #pragma unroll
    for (int cg = 0; cg < 8; cg++) {
        int col = colb + cg * 16 + l15;
        int hh = col >> 5, dh = col & 31;
        float bs = bias[col];
        if (z < 2) {
            _Float16* op = (z == 0) ? qbuf : kbuf;
            #pragma unroll
            for (int r = 0; r < 4; r++) {
                int n = rowb + wv2 * 16 + quad * 4 + r - bb * N;
                float v = (acc[cg][r] + bs) * scale;
                op[((size_t)(bb * H + hh) * N + n) * DH + dh] = (_Float16)v;
            }
        } else {
            int n0 = rowb + wv2 * 16 + quad * 4 - bb * N;
            half4_t pk;
            #pragma unroll
            for (int r = 0; r < 4; r++) pk[r] = (_Float16)(acc[cg][r] + bs);
            *(half4_t*)(vtbuf + ((size_t)(bb * H + hh) * DH + dh) * N + n0) = pk;
        }
    }
}

// ---------------------------------------------------------------------------
// Flash attention (S^T register-P), 128-key LDS tiles (3 barrier-pairs per
// block instead of 6). grid (18, BH, KS), 256 thr = 4 waves x 32 queries.
// QK^T: one 16x16x32 mfma per 16-key group; exp2 in place; P^T C-frag feeds
// PV (A=V^T from LDS, K=16 mfma). Fixed-max softmax, fp16 split-K partials.
// ---------------------------------------------------------------------------
__global__ __launch_bounds__(256) void attn_kernel(
    const _Float16* __restrict__ qbuf, const _Float16* __restrict__ kbuf,
    const _Float16* __restrict__ vtbuf,
    _Float16* __restrict__ ctx_part, float* __restrict__ lpart)
{
    __shared__ __align__(16) _Float16 Ks[128 * 40];   // 10 KB
    __shared__ __align__(16) _Float16 Vt[32 * 136];   // 8.5 KB [d][key]

    const int t = threadIdx.x;
    const int wv2 = t >> 6, lane = t & 63, l15 = lane & 15, quad = lane >> 4;
    const int bh = blockIdx.y, kz = blockIdx.z;
    const int qbase = blockIdx.x * 128 + wv2 * 32;

    half8 bq8[2];
    #pragma unroll
    for (int qg = 0; qg < 2; qg++)
        bq8[qg] = *(const half8*)(qbuf +
            ((size_t)bh * N + qbase + qg * 16 + l15) * DH + quad * 8);

    floatx4 acc[2][2] = {{{0,0,0,0},{0,0,0,0}},{{0,0,0,0},{0,0,0,0}}};
    float lsum[2] = {0.f, 0.f};

    for (int it = 0; it < KPZ / 128; it++) {
        const int key0 = kz * KPZ + it * 128;
        __syncthreads();
        #pragma unroll
        for (int i = 0; i < 2; i++) {
            int u = i * 256 + t;
            // K: key = u>>2 (0..127), part = u&3
            *(ushort8_t*)(Ks + (u >> 2) * 40 + (u & 3) * 8) =
                *(const ushort8_t*)(kbuf + ((size_t)bh * N + key0 + (u >> 2)) * DH + (u & 3) * 8);
            // V: d = u>>4 (0..31), kp = u&15
            *(ushort8_t*)(Vt + (u >> 4) * 136 + (u & 15) * 8) =
                *(const ushort8_t*)(vtbuf + ((size_t)bh * DH + (u >> 4)) * N + key0 + (u & 15) * 8);
        }
        __syncthreads();

        #pragma unroll
        for (int kg = 0; kg < 8; kg++) {
            half8 ka = *(const half8*)(Ks + (kg * 16 + l15) * 40 + quad * 8);
            half4_t va0 = *(const half4_t*)(Vt + l15 * 136 + kg * 16 + quad * 4);
            half4_t va1 = *(const half4_t*)(Vt + (16 + l15) * 136 + kg * 16 + quad * 4);
            #pragma unroll
            for (int qg = 0; qg < 2; qg++) {
                floatx4 s = {0, 0, 0, 0};
                s = __builtin_amdgcn_mfma_f32_16x16x32_f16(ka, bq8[qg], s, 0, 0, 0);
                half4_t pf;
                #pragma unroll
                for (int r = 0; r < 4; r++) {
                    float p = exp2f(s[r]);
                    lsum[qg] += p;
                    pf[r] = (_Float16)p;
                }
                acc[qg][0] = __builtin_amdgcn_mfma_f32_16x16x16f16(va0, pf, acc[qg][0], 0, 0, 0);
                acc[qg][1] = __builtin_amdgcn_mfma_f32_16x16x16f16(va1, pf, acc[qg][1], 0, 0, 0);
            }
        }
    }

    const int bb = bh >> 3, hh = bh & 7;
    #pragma unroll
    for (int qg = 0; qg < 2; qg++) {
        float ls = lsum[qg];
        ls += __shfl_xor(ls, 16);
        ls += __shfl_xor(ls, 32);
        int q = qbase + qg * 16 + l15;
        if (quad == 0) lpart[(size_t)kz * BHN + bh * N + q] = ls;
        _Float16* crow = ctx_part + (size_t)kz * NE + ((size_t)bb * N + q) * D + hh * DH;
        half4_t c0, c1;
        #pragma unroll
        for (int r = 0; r < 4; r++) {
            c0[r] = (_Float16)acc[qg][0][r];
            c1[r] = (_Float16)acc[qg][1][r];
        }
        *(half4_t*)(crow + quad * 4)      = c0;
        *(half4_t*)(crow + 16 + quad * 4) = c1;
    }
}

// ---------------------------------------------------------------------------
// Output projection with fused merge, 32x128 tiles (ctx_part re-read 2x
// instead of 4x): A merged+normalized into LDS once per k-chunk, shared by
// both column-half waves. grid (144, 2). out fp32.
// ---------------------------------------------------------------------------
__global__ __launch_bounds__(256) void outproj_kernel(
    const _Float16* __restrict__ ctx_part, const float* __restrict__ lpart,
    const float* __restrict__ Wo, const float* __restrict__ bo,
    float* __restrict__ out)
{
    __shared__ __align__(16) _Float16 BhS[128 * 72];   // 18.4 KB
    __shared__ __align__(16) _Float16 AsS[32 * 72];    // 4.6 KB
    __shared__ float Linv[32 * 8];

    const int t = threadIdx.x;
    const int wv2 = t >> 6, lane = t & 63, l15 = lane & 15, quad = lane >> 4;
    const int wr = wv2 >> 1, wc = wv2 & 1;   // row-half / col-half of the wave
    const int rowb = blockIdx.x * 32;
    const int colb = blockIdx.y * 128;

    // per-block merged 1/l table: rows 0..31 x heads 0..7
    {
        int r = t >> 3, hh = t & 7;
        int row = rowb + r;
        int bb = (row >= N) ? 1 : 0;
        int bhn = (bb * H + hh) * N + (row - bb * N);
        float ls = 0.f;
        #pragma unroll
        for (int zz = 0; zz < KS; zz++) ls += lpart[(size_t)zz * BHN + bhn];
        Linv[t] = 1.0f / ls;
    }

    floatx4 acc[4] = {{0,0,0,0},{0,0,0,0},{0,0,0,0},{0,0,0,0}};

    for (int kb0 = 0; kb0 < D; kb0 += 64) {
        __syncthreads();
        // A: merge KS fp16 partials, normalize, to LDS (32 rows x 64 k)
        {
            int r = t >> 3, k0 = (t & 7) * 8;
            int row = rowb + r;
            int kcol = kb0 + k0;
            float linv = Linv[r * 8 + (kcol >> 5)];
            float v[8] = {};
            #pragma unroll
            for (int zz = 0; zz < KS; zz++) {
                half8 h = *(const half8*)(ctx_part + (size_t)zz * NE + (size_t)row * D + kcol);
                #pragma unroll
                for (int j = 0; j < 8; j++) v[j] += (float)h[j];
            }
            #pragma unroll
            for (int j = 0; j < 8; j++) v[j] *= linv;
            *(half8*)(AsS + r * 72 + k0) = cvt8(v);
        }
        // B: Wo transposed gather (128 cols x 64 k)
        #pragma unroll
        for (int i = 0; i < 4; i++) {
            int u = i * 256 + t;
            int cc = u & 127, k0 = (u >> 7) * 8;
            float v[8];
            #pragma unroll
            for (int j = 0; j < 8; j++)
                v[j] = Wo[(size_t)(kb0 + k0 + j) * D + colb + cc];
            *(half8*)(BhS + cc * 72 + k0) = cvt8(v);
        }
        __syncthreads();
        #pragma unroll
        for (int ksx = 0; ksx < 2; ksx++) {
            half8 ah = *(const half8*)(AsS + (wr * 16 + l15) * 72 + ksx * 32 + quad * 8);
            #pragma unroll
            for (int cg = 0; cg < 4; cg++) {
                half8 bh8 = *(const half8*)(BhS + (wc * 64 + cg * 16 + l15) * 72 + ksx * 32 + quad * 8);
                acc[cg] = __builtin_amdgcn_mfma_f32_16x16x32_f16(ah, bh8, acc[cg], 0, 0, 0);
            }
        }
    }

    #pragma unroll
    for (int cg = 0; cg < 4; cg++) {
        int col = colb + wc * 64 + cg * 16 + l15;
        float bs = bo[col];
        #pragma unroll
        for (int r = 0; r < 4; r++) {
            int row = rowb + wr * 16 + quad * 4 + r;
            out[(size_t)row * D + col] = acc[cg][r] + bs;
        }
    }
}

extern "C" void kernel_launch(void* const* d_in, const int* in_sizes, int n_in,
                              void* d_out, int out_size, void* d_ws, size_t ws_size,
                              hipStream_t stream)
{
    const float* x  = (const float*)d_in[0];
    const float* Wq = (const float*)d_in[1];
    const float* bq = (const float*)d_in[2];
    const float* Wk = (const float*)d_in[3];
    const float* bk = (const float*)d_in[4];
    const float* Wv = (const float*)d_in[5];
    const float* bv = (const float*)d_in[6];
    const float* Wo = (const float*)d_in[7];
    const float* bo = (const float*)d_in[8];
    float* out = (float*)d_out;

    _Float16* ctx_part = (_Float16*)d_ws;                   // KS*NE halfs
    float* lpart    = (float*)(ctx_part + (size_t)KS * NE); // KS*BHN fp32
    _Float16* qbuf  = (_Float16*)(lpart + (size_t)KS * BHN);
    _Float16* kbuf  = qbuf + NE;
    _Float16* vtbuf = kbuf + NE;

    proj_kernel<<<dim3(BN / 64, D / 128, 3), 256, 0, stream>>>(
        x, Wq, bq, Wk, bk, Wv, bv, qbuf, kbuf, vtbuf);

    attn_kernel<<<dim3(N / 128, BH, KS), 256, 0, stream>>>(
        qbuf, kbuf, vtbuf, ctx_part, lpart);

    outproj_kernel<<<dim3(BN / 32, D / 128), 256, 0, stream>>>(
        ctx_part, lpart, Wo, bo, out);
}